// Round 2
// baseline (2690.561 us; speedup 1.0000x reference)
//
#include <hip/hip_runtime.h>
#include <hip/hip_bf16.h>
#include <stdint.h>

// Problem constants (LSTM_36825049596199)
#define B_    64
#define T_    512
#define EMB_  128
#define H_    128
#define G4    512            // 4*H
#define M_    (B_ * T_)      // 32768 rows for the input-projection GEMM

typedef __attribute__((ext_vector_type(8))) short     short8;   // 8 bf16 MFMA frag
typedef __attribute__((ext_vector_type(4))) float     floatx4;  // MFMA acc frag
typedef __attribute__((ext_vector_type(2))) _Float16  half2v;   // packed f16
typedef __attribute__((ext_vector_type(8))) _Float16  half8;    // 8 f16 MFMA frag

#define GLDS(g, l) __builtin_amdgcn_global_load_lds( \
    (__attribute__((address_space(1))) void*)(g),    \
    (__attribute__((address_space(3))) void*)(l), 16, 0, 0)

__device__ __forceinline__ unsigned short f2bf_bits(float f) {
  __hip_bfloat16 h = __float2bfloat16(f);
  return *reinterpret_cast<unsigned short*>(&h);
}
__device__ __forceinline__ float bf_bits2f(unsigned short u) {
  unsigned int x = ((unsigned int)u) << 16;
  return __uint_as_float(x);
}
__device__ __forceinline__ float sigm(float x) {
  return __fdividef(1.0f, 1.0f + __expf(-x));
}
__device__ __forceinline__ float tanh_fast(float x) {
  return 1.0f - __fdividef(2.0f, __expf(2.0f * x) + 1.0f);
}
__device__ __forceinline__ unsigned int pack_f16x2(float a, float b) {
  half2v h; h.x = (_Float16)a; h.y = (_Float16)b;
  return __builtin_bit_cast(unsigned int, h);
}

// LDS-only barrier. 0xC07F: vmcnt=63, expcnt=7, lgkmcnt=0 — drains LDS ops
// (h exchange) but leaves global xg prefetches / y stores in flight.
__device__ __forceinline__ void barrier_lds_only() {
  __builtin_amdgcn_s_waitcnt(0xC07F);
  __builtin_amdgcn_s_barrier();
}

// ---------------------------------------------------------------------------
// Embedding gather: x0[b,t,:] = bf16(emb[X[b,t],:]).
__global__ void k_gather(const int* __restrict__ X, const float* __restrict__ emb,
                         unsigned short* __restrict__ x0) {
  int i = blockIdx.x * 256 + threadIdx.x;
  int row = i >> 5, c4 = i & 31;
  float4 v = ((const float4*)emb)[(size_t)X[row] * 32 + c4];
  ushort4 o;
  o.x = f2bf_bits(v.x); o.y = f2bf_bits(v.y); o.z = f2bf_bits(v.z); o.w = f2bf_bits(v.w);
  ((ushort4*)x0)[i] = o;
}

// Per-layer prep: w_ih -> bf16, bias_sum = b_ih + b_hh.
__global__ void k_prep(const float* __restrict__ w, const float* __restrict__ bi,
                       const float* __restrict__ bh, unsigned short* __restrict__ wb,
                       float* __restrict__ bias, int nw) {
  int i = blockIdx.x * blockDim.x + threadIdx.x;
  int stride = gridDim.x * blockDim.x;
  for (int k = i; k < nw; k += stride) wb[k] = f2bf_bits(w[k]);
  for (int k = i; k < 2 * G4; k += stride) bias[k] = bi[k] + bh[k];
}

// W_hh f16 B-fragment pack for the MFMA scan.
// B-frag for (dir, wave w, gate g, k-slice kk): lane l supplies
// B[k = 32kk + (l>>4)*8 + j][col] = Whh[dir][g*128 + 16w + (l&15)][k], j=0..7.
// Flat uint index = ((((dir*8+w)*4+g)*4+kk)*64 + l)*4 + jp  (jp = j/2 pair).
__global__ void k_prep_whh(const float* __restrict__ Whh, unsigned int* __restrict__ wf) {
  int i = blockIdx.x * 256 + threadIdx.x;   // [0, 65536)
  int jp  = i & 3;
  int l   = (i >> 2) & 63;
  int kk  = (i >> 8) & 3;
  int g   = (i >> 10) & 3;
  int w   = (i >> 12) & 7;
  int dir = (i >> 15) & 1;
  int row = g * 128 + w * 16 + (l & 15);
  int k0  = kk * 32 + (l >> 4) * 8 + 2 * jp;
  const float* wr = Whh + ((size_t)dir * G4 + row) * H_ + k0;
  wf[i] = pack_f16x2(wr[0], wr[1]);
}

// ---------------------------------------------------------------------------
// Input-projection GEMM (NT) — unchanged m97-style; xg stored bf16, gate-major.
__global__ __launch_bounds__(256, 2) void k_gemm(
    const unsigned short* __restrict__ A,   // [M_, K] bf16 row-major
    const unsigned short* __restrict__ W,   // [2][G4][K] bf16 row-major
    const float* __restrict__ bias,         // [2][G4]
    unsigned short* __restrict__ xg,        // [2][M_][G4] bf16
    int K) {
  __shared__ unsigned short sA[128 * 32];
  __shared__ unsigned short sB[128 * 32];
  const int tid  = threadIdx.x;
  const int lane = tid & 63;
  const int wave = tid >> 6;
  const int mt = blockIdx.x, nt = blockIdx.y, dir = blockIdx.z;
  const size_t Arow0 = (size_t)mt * 128;
  const int    Ncol0 = nt * 128;
  const unsigned short* Wd = W + (size_t)dir * G4 * K;

  const int srow = tid >> 2;
  const int qlog = (tid & 3) ^ ((tid >> 4) & 3);
  auto ldsA0 = (__attribute__((address_space(3))) void*)(sA + wave * 512);
  auto ldsA1 = (__attribute__((address_space(3))) void*)(sA + 2048 + wave * 512);
  auto ldsB0 = (__attribute__((address_space(3))) void*)(sB + wave * 512);
  auto ldsB1 = (__attribute__((address_space(3))) void*)(sB + 2048 + wave * 512);

  floatx4 acc[4][4];
#pragma unroll
  for (int i = 0; i < 4; ++i)
#pragma unroll
    for (int j = 0; j < 4; ++j) acc[i][j] = (floatx4)0.0f;

  const int wrow = (wave >> 1) * 64, wcol = (wave & 1) * 64;
  const int frow = lane & 15;
  const int fq   = lane >> 4;

  for (int kt = 0; kt < K; kt += 32) {
    const unsigned short* gA0 = A  + (Arow0 + srow) * (size_t)K + kt + qlog * 8;
    const unsigned short* gB0 = Wd + (size_t)(Ncol0 + srow) * K + kt + qlog * 8;
    GLDS(gA0, ldsA0);
    GLDS(gA0 + (size_t)64 * K, ldsA1);
    GLDS(gB0, ldsB0);
    GLDS(gB0 + (size_t)64 * K, ldsB1);
    __syncthreads();

    short8 af[4], bf[4];
#pragma unroll
    for (int i = 0; i < 4; ++i) {
      int r  = wrow + 16 * i + frow;
      int rn = wcol + 16 * i + frow;
      af[i] = *(const short8*)(sA + r  * 32 + ((fq ^ ((r  >> 2) & 3)) * 8));
      bf[i] = *(const short8*)(sB + rn * 32 + ((fq ^ ((rn >> 2) & 3)) * 8));
    }
#pragma unroll
    for (int i = 0; i < 4; ++i)
#pragma unroll
      for (int j = 0; j < 4; ++j)
        acc[i][j] = __builtin_amdgcn_mfma_f32_16x16x32_bf16(af[i], bf[j], acc[i][j], 0, 0, 0);
    __syncthreads();
  }

  const int r0 = (lane >> 4) * 4;
  const int cc = lane & 15;
  unsigned short* xgd = xg + (size_t)dir * M_ * G4;
#pragma unroll
  for (int j = 0; j < 4; ++j) {
    int gcol = Ncol0 + wcol + 16 * j + cc;
    float bs = bias[dir * G4 + gcol];
#pragma unroll
    for (int i = 0; i < 4; ++i) {
      size_t rowb = Arow0 + wrow + 16 * i + r0;
#pragma unroll
      for (int r = 0; r < 4; ++r)
        xgd[(rowb + r) * G4 + gcol] = f2bf_bits(acc[i][j][r] + bs);
    }
  }
}

// ---------------------------------------------------------------------------
// Recurrent scan — R14: 16-batch MFMA scan.
// R12/R13 post-mortem: per-step wall is the serial critical path; per-seq
// fdot2 issue (128 inst/step for ONE batch) + tails = ~1460cy/step. R14
// amortizes: one block = 16 batches of one dir; per step the recurrent
// matmul H[16x128] x Whh^T[128x512] runs on the MATRIX pipe as 128
// mfma_f32_16x16x32_f16 (16/wave, 8 waves), h kept f16 (same numerics as
// R12's f16 dot). Per-step floor moves to the trans unit (16x128 cell
// updates x ~10 trans = ~640cy/SIMD) — for 16 batches at once vs 1462cy
// for 1 batch before. 8 blocks (2 dir x 4 groups), 1 lgkm-only barrier/step,
// H double-buffered in LDS with XOR chunk swizzle (row-major [16][128]
// would bank-conflict on the A-frag ds_read_b128). xg register-prefetched
// 2 steps ahead; per-lane offsets loop-invariant, time advances via a
// wave-uniform base pointer.
// MFMA lane mappings mirrored from the WORKING k_gemm above:
//   A: row=lane&15, k=(lane>>4)*8+j ; B: col=lane&15, same k ;
//   C: row=(lane>>4)*4+r, col=lane&15.
__global__ __launch_bounds__(512, 2) void k_scan(
    const unsigned int* __restrict__ wf,   // packed f16 B-frags (k_prep_whh)
    const float* __restrict__ hx0,         // [2][B_][H_] (layer base)
    const float* __restrict__ cx0,
    const unsigned short* __restrict__ xg, // [2][M_][G4] bf16 gate-major
    unsigned short* __restrict__ y)        // [B_][T_][2*H_] bf16
{
  const int dir = blockIdx.x >> 2;          // 8 blocks: 2 dirs x 4 groups
  const int b0  = (blockIdx.x & 3) * 16;    // batch group base
  const int tid  = threadIdx.x;
  const int lane = tid & 63;
  const int w    = tid >> 6;                // wave 0..7 = unit-tile
  const int lq   = lane >> 4;               // lane quarter
  const int cc   = lane & 15;
  const int u    = 16 * w + cc;             // this lane's unit column

  __shared__ __align__(16) unsigned short Hs[2][16 * 128];  // f16, swizzled

  // Resident weights: B-frags for 4 gates x 4 k-slices (64 VGPR).
  half8 wB[4][4];
  {
    const uint4* wv = (const uint4*)wf;
    const int base = (dir * 8 + w) * 16;
#pragma unroll
    for (int g = 0; g < 4; ++g)
#pragma unroll
      for (int kk = 0; kk < 4; ++kk)
        wB[g][kk] = __builtin_bit_cast(half8, wv[(base + g * 4 + kk) * 64 + lane]);
  }

  // c state: 4 batches (rows lq*4+r) x 1 unit.
  float c[4];
#pragma unroll
  for (int r = 0; r < 4; ++r)
    c[r] = cx0[(size_t)dir * B_ * H_ + (b0 + lq * 4 + r) * H_ + u];

  // H init: thread writes 4 f16 (row tid>>5, cols (tid&31)*4..+4), swizzled.
  {
    int row = tid >> 5;
    int c0  = (tid & 31) * 4;
    const float* hp = hx0 + (size_t)dir * B_ * H_ + (b0 + row) * H_ + c0;
    float4 hv = *(const float4*)hp;
    uint2 pk;
    pk.x = pack_f16x2(hv.x, hv.y);
    pk.y = pack_f16x2(hv.z, hv.w);
    int byteoff = (row * 256 + c0 * 2) ^ ((row & 7) << 4);
    *(uint2*)((char*)&Hs[0][0] + byteoff) = pk;
  }

  // Loop-invariant addresses.
  int aoff[4];                               // A-frag ds_read_b128 byte offsets
#pragma unroll
  for (int kk = 0; kk < 4; ++kk)
    aoff[kk] = (cc * 256 + kk * 64 + lq * 16) ^ ((cc & 7) << 4);

  int hwidx[4];                              // h write ushort indices (swizzled)
#pragma unroll
  for (int r = 0; r < 4; ++r) {
    int row = lq * 4 + r;
    hwidx[r] = ((row * 256 + u * 2) ^ ((row & 7) << 4)) >> 1;
  }

  const unsigned short* xgd = xg + (size_t)dir * M_ * G4;
  int xofs[4][4];                            // [gate][batch-row]
#pragma unroll
  for (int g = 0; g < 4; ++g)
#pragma unroll
    for (int r = 0; r < 4; ++r)
      xofs[g][r] = (b0 + lq * 4 + r) * (T_ * G4) + g * H_ + u;

  int yofs[4];
#pragma unroll
  for (int r = 0; r < 4; ++r)
    yofs[r] = (b0 + lq * 4 + r) * (T_ * 2 * H_) + dir * H_ + u;

  const int td = dir ? -1 : 1;
  int t0 = dir ? (T_ - 1) : 0;

  // xg register prefetch, distance 2 (overruns stay inside the xg buffer).
  unsigned short xpA[4][4], xpB[4][4];
  {
    const unsigned short* p0 = xgd + (intptr_t)t0 * G4;
    const unsigned short* p1 = xgd + (intptr_t)(t0 + td) * G4;
#pragma unroll
    for (int g = 0; g < 4; ++g)
#pragma unroll
      for (int r = 0; r < 4; ++r) {
        xpA[g][r] = p0[xofs[g][r]];
        xpB[g][r] = p1[xofs[g][r]];
      }
  }

  __syncthreads();   // init h visible (full drain fine, once)

  auto step = [&](int par, int tcur, unsigned short (&xp)[4][4]) {
    // A fragments (h_{t-1}) + MFMA: 4 gates x 4 k-slices, 4 indep acc chains.
    half8 a[4];
#pragma unroll
    for (int kk = 0; kk < 4; ++kk)
      a[kk] = __builtin_bit_cast(half8,
          *(const uint4*)((const char*)&Hs[par][0] + aoff[kk]));
    floatx4 ac[4];
#pragma unroll
    for (int g = 0; g < 4; ++g) ac[g] = (floatx4)0.0f;
#pragma unroll
    for (int kk = 0; kk < 4; ++kk)
#pragma unroll
      for (int g = 0; g < 4; ++g)
        ac[g] = __builtin_amdgcn_mfma_f32_16x16x32_f16(a[kk], wB[g][kk], ac[g], 0, 0, 0);

    // Capture xg(t), then prefetch xg(t+2) into the same regs.
    float xv[4][4];
#pragma unroll
    for (int g = 0; g < 4; ++g)
#pragma unroll
      for (int r = 0; r < 4; ++r) xv[g][r] = bf_bits2f(xp[g][r]);
    {
      const unsigned short* pn = xgd + (intptr_t)(tcur + 2 * td) * G4;
#pragma unroll
      for (int g = 0; g < 4; ++g)
#pragma unroll
        for (int r = 0; r < 4; ++r) xp[g][r] = pn[xofs[g][r]];
    }

    // Cell updates: 4 (batch, unit) cells per lane.
    unsigned short* ydst = y + (size_t)tcur * (2 * H_);
    unsigned short* hdst = &Hs[par ^ 1][0];
#pragma unroll
    for (int r = 0; r < 4; ++r) {
      float gi = ac[0][r] + xv[0][r];
      float gf = ac[1][r] + xv[1][r];
      float gg = ac[2][r] + xv[2][r];
      float go = ac[3][r] + xv[3][r];
      float iv = sigm(gi), fv = sigm(gf), gv = tanh_fast(gg), ov = sigm(go);
      c[r] = fmaf(fv, c[r], iv * gv);
      float h = ov * tanh_fast(c[r]);
      hdst[hwidx[r]] = (unsigned short)(pack_f16x2(h, 0.0f) & 0xFFFF);
      ydst[yofs[r]] = f2bf_bits(h);
    }
    barrier_lds_only();
  };

  for (int it = 0; it < T_; it += 2) {
    step(0, t0, xpA);
    step(1, t0 + td, xpB);
    t0 += 2 * td;
  }
}

// ---------------------------------------------------------------------------
// Head: out[b] = y2[b, T-1, :] . lin_w + lin_b
__global__ void k_head(const unsigned short* __restrict__ y2, const float* __restrict__ lw,
                       const float* __restrict__ lb, float* __restrict__ out) {
  int b = blockIdx.x, l = threadIdx.x;
  const unsigned short* row = y2 + ((size_t)b * T_ + (T_ - 1)) * (2 * H_);
  float s = 0;
#pragma unroll
  for (int k = 0; k < 4; ++k) s += bf_bits2f(row[l + 64 * k]) * lw[l + 64 * k];
#pragma unroll
  for (int off = 32; off > 0; off >>= 1) s += __shfl_down(s, off);
  if (l == 0) out[b] = s + lb[0];
}

// ---------------------------------------------------------------------------
static inline void run_layers(const unsigned int* const* wfs,
                              const unsigned short* x0,
                              unsigned short* y0, unsigned short* y1, unsigned short* y2,
                              const unsigned short* wb0, const unsigned short* wb1,
                              const unsigned short* wb2,
                              const float* bias0, const float* bias1, const float* bias2,
                              const float* hx, const float* cx,
                              unsigned short* xg, hipStream_t stream) {
  dim3 gg(M_ / 128, G4 / 128, 2);
  k_gemm<<<gg, 256, 0, stream>>>(x0, wb0, bias0, xg, EMB_);
  k_scan<<<8, 512, 0, stream>>>(wfs[0], hx, cx, xg, y0);
  k_gemm<<<gg, 256, 0, stream>>>(y0, wb1, bias1, xg, 2 * H_);
  k_scan<<<8, 512, 0, stream>>>(wfs[1], hx + 2 * B_ * H_, cx + 2 * B_ * H_, xg, y1);
  k_gemm<<<gg, 256, 0, stream>>>(y1, wb2, bias2, xg, 2 * H_);
  k_scan<<<8, 512, 0, stream>>>(wfs[2], hx + 4 * B_ * H_, cx + 4 * B_ * H_, xg, y2);
}

extern "C" void kernel_launch(void* const* d_in, const int* in_sizes, int n_in,
                              void* d_out, int out_size, void* d_ws, size_t ws_size,
                              hipStream_t stream) {
  const int*   X   = (const int*)d_in[0];
  const float* emb = (const float*)d_in[1];
  const float* hx  = (const float*)d_in[2];
  const float* cx  = (const float*)d_in[3];
  const float* lw  = (const float*)d_in[4];
  const float* lb  = (const float*)d_in[5];
  const float* w_ih[3] = {(const float*)d_in[6],  (const float*)d_in[10], (const float*)d_in[14]};
  const float* w_hh[3] = {(const float*)d_in[7],  (const float*)d_in[11], (const float*)d_in[15]};
  const float* b_ih[3] = {(const float*)d_in[8],  (const float*)d_in[12], (const float*)d_in[16]};
  const float* b_hh[3] = {(const float*)d_in[9],  (const float*)d_in[13], (const float*)d_in[17]};
  float* out = (float*)d_out;

  char* ws = (char*)d_ws;
  size_t off = 0;
  auto carve = [&](size_t bytes) {
    char* p = ws + off;
    off = (off + bytes + 255) & ~(size_t)255;
    return p;
  };
  unsigned short* x0  = (unsigned short*)carve((size_t)M_ * EMB_ * 2);
  unsigned short* y0  = (unsigned short*)carve((size_t)M_ * 2 * H_ * 2);
  unsigned short* y1  = (unsigned short*)carve((size_t)M_ * 2 * H_ * 2);
  unsigned short* y2  = (unsigned short*)carve((size_t)M_ * 2 * H_ * 2);
  unsigned short* wb0 = (unsigned short*)carve((size_t)2 * G4 * EMB_ * 2);
  unsigned short* wb1 = (unsigned short*)carve((size_t)2 * G4 * 2 * H_ * 2);
  unsigned short* wb2 = (unsigned short*)carve((size_t)2 * G4 * 2 * H_ * 2);
  float* bias0 = (float*)carve(2 * G4 * 4);
  float* bias1 = (float*)carve(2 * G4 * 4);
  float* bias2 = (float*)carve(2 * G4 * 4);
  unsigned int* wf0 = (unsigned int*)carve((size_t)65536 * 4);
  unsigned int* wf1 = (unsigned int*)carve((size_t)65536 * 4);
  unsigned int* wf2 = (unsigned int*)carve((size_t)65536 * 4);
  unsigned short* xg = (unsigned short*)carve((size_t)2 * M_ * G4 * 2);  // bf16

  k_prep<<<256, 256, 0, stream>>>(w_ih[0], b_ih[0], b_hh[0], wb0, bias0, 2 * G4 * EMB_);
  k_prep<<<256, 256, 0, stream>>>(w_ih[1], b_ih[1], b_hh[1], wb1, bias1, 2 * G4 * 2 * H_);
  k_prep<<<256, 256, 0, stream>>>(w_ih[2], b_ih[2], b_hh[2], wb2, bias2, 2 * G4 * 2 * H_);
  k_prep_whh<<<256, 256, 0, stream>>>(w_hh[0], wf0);
  k_prep_whh<<<256, 256, 0, stream>>>(w_hh[1], wf1);
  k_prep_whh<<<256, 256, 0, stream>>>(w_hh[2], wf2);
  k_gather<<<(M_ * 32) / 256, 256, 0, stream>>>(X, emb, x0);

  const unsigned int* wfs[3] = {wf0, wf1, wf2};
  run_layers(wfs, x0, y0, y1, y2, wb0, wb1, wb2, bias0, bias1, bias2,
             hx, cx, xg, stream);

  k_head<<<64, 64, 0, stream>>>(y2, lw, lb, out);
}

// Round 3
// 1615.199 us; speedup vs baseline: 1.6658x; 1.6658x over previous
//
#include <hip/hip_runtime.h>
#include <hip/hip_bf16.h>
#include <stdint.h>

// Problem constants (LSTM_36825049596199)
#define B_    64
#define T_    512
#define EMB_  128
#define H_    128
#define G4    512            // 4*H
#define M_    (B_ * T_)      // 32768 rows for the input-projection GEMM

typedef __attribute__((ext_vector_type(8))) short     short8;   // 8 bf16 MFMA frag
typedef __attribute__((ext_vector_type(4))) float     floatx4;  // MFMA acc frag
typedef __attribute__((ext_vector_type(2))) _Float16  half2v;   // packed f16
typedef __attribute__((ext_vector_type(8))) _Float16  half8;    // 8 f16 MFMA frag

#define GLDS(g, l) __builtin_amdgcn_global_load_lds( \
    (__attribute__((address_space(1))) void*)(g),    \
    (__attribute__((address_space(3))) void*)(l), 16, 0, 0)

__device__ __forceinline__ unsigned short f2bf_bits(float f) {
  __hip_bfloat16 h = __float2bfloat16(f);
  return *reinterpret_cast<unsigned short*>(&h);
}
__device__ __forceinline__ float bf_bits2f(unsigned short u) {
  unsigned int x = ((unsigned int)u) << 16;
  return __uint_as_float(x);
}
__device__ __forceinline__ float sigm(float x) {
  return __fdividef(1.0f, 1.0f + __expf(-x));
}
__device__ __forceinline__ float tanh_fast(float x) {
  return 1.0f - __fdividef(2.0f, __expf(2.0f * x) + 1.0f);
}
__device__ __forceinline__ unsigned int pack_f16x2(float a, float b) {
  half2v h; h.x = (_Float16)a; h.y = (_Float16)b;
  return __builtin_bit_cast(unsigned int, h);
}

// LDS-only barrier. 0xC07F: vmcnt=63, expcnt=7, lgkmcnt=0 — drains LDS ops
// (h exchange, bpermute) but leaves global xg prefetches / y stores in flight.
__device__ __forceinline__ void barrier_lds_only() {
  __builtin_amdgcn_s_waitcnt(0xC07F);
  __builtin_amdgcn_s_barrier();
}

// ---------------------------------------------------------------------------
// Embedding gather: x0[b,t,:] = bf16(emb[X[b,t],:]).
__global__ void k_gather(const int* __restrict__ X, const float* __restrict__ emb,
                         unsigned short* __restrict__ x0) {
  int i = blockIdx.x * 256 + threadIdx.x;
  int row = i >> 5, c4 = i & 31;
  float4 v = ((const float4*)emb)[(size_t)X[row] * 32 + c4];
  ushort4 o;
  o.x = f2bf_bits(v.x); o.y = f2bf_bits(v.y); o.z = f2bf_bits(v.z); o.w = f2bf_bits(v.w);
  ((ushort4*)x0)[i] = o;
}

// Per-layer prep: w_ih -> bf16, bias_sum = b_ih + b_hh.
__global__ void k_prep(const float* __restrict__ w, const float* __restrict__ bi,
                       const float* __restrict__ bh, unsigned short* __restrict__ wb,
                       float* __restrict__ bias, int nw) {
  int i = blockIdx.x * blockDim.x + threadIdx.x;
  int stride = gridDim.x * blockDim.x;
  for (int k = i; k < nw; k += stride) wb[k] = f2bf_bits(w[k]);
  for (int k = i; k < 2 * G4; k += stride) bias[k] = bi[k] + bh[k];
}

// W_hh f16 B-fragment pack for the MFMA scan (verified correct in R14).
// B-frag for (dir, wave w, gate g, k-slice kk): lane l supplies
// B[k = 32kk + (l>>4)*8 + j][col] = Whh[dir][g*128 + 16w + (l&15)][k], j=0..7.
// Flat uint index = ((((dir*8+w)*4+g)*4+kk)*64 + l)*4 + jp  (jp = j/2 pair).
__global__ void k_prep_whh(const float* __restrict__ Whh, unsigned int* __restrict__ wf) {
  int i = blockIdx.x * 256 + threadIdx.x;   // [0, 65536)
  int jp  = i & 3;
  int l   = (i >> 2) & 63;
  int kk  = (i >> 8) & 3;
  int g   = (i >> 10) & 3;
  int w   = (i >> 12) & 7;
  int dir = (i >> 15) & 1;
  int row = g * 128 + w * 16 + (l & 15);
  int k0  = kk * 32 + (l >> 4) * 8 + 2 * jp;
  const float* wr = Whh + ((size_t)dir * G4 + row) * H_ + k0;
  wf[i] = pack_f16x2(wr[0], wr[1]);
}

// ---------------------------------------------------------------------------
// Input-projection GEMM (NT) — unchanged m97-style; xg stored bf16, gate-major.
__global__ __launch_bounds__(256, 2) void k_gemm(
    const unsigned short* __restrict__ A,   // [M_, K] bf16 row-major
    const unsigned short* __restrict__ W,   // [2][G4][K] bf16 row-major
    const float* __restrict__ bias,         // [2][G4]
    unsigned short* __restrict__ xg,        // [2][M_][G4] bf16
    int K) {
  __shared__ unsigned short sA[128 * 32];
  __shared__ unsigned short sB[128 * 32];
  const int tid  = threadIdx.x;
  const int lane = tid & 63;
  const int wave = tid >> 6;
  const int mt = blockIdx.x, nt = blockIdx.y, dir = blockIdx.z;
  const size_t Arow0 = (size_t)mt * 128;
  const int    Ncol0 = nt * 128;
  const unsigned short* Wd = W + (size_t)dir * G4 * K;

  const int srow = tid >> 2;
  const int qlog = (tid & 3) ^ ((tid >> 4) & 3);
  auto ldsA0 = (__attribute__((address_space(3))) void*)(sA + wave * 512);
  auto ldsA1 = (__attribute__((address_space(3))) void*)(sA + 2048 + wave * 512);
  auto ldsB0 = (__attribute__((address_space(3))) void*)(sB + wave * 512);
  auto ldsB1 = (__attribute__((address_space(3))) void*)(sB + 2048 + wave * 512);

  floatx4 acc[4][4];
#pragma unroll
  for (int i = 0; i < 4; ++i)
#pragma unroll
    for (int j = 0; j < 4; ++j) acc[i][j] = (floatx4)0.0f;

  const int wrow = (wave >> 1) * 64, wcol = (wave & 1) * 64;
  const int frow = lane & 15;
  const int fq   = lane >> 4;

  for (int kt = 0; kt < K; kt += 32) {
    const unsigned short* gA0 = A  + (Arow0 + srow) * (size_t)K + kt + qlog * 8;
    const unsigned short* gB0 = Wd + (size_t)(Ncol0 + srow) * K + kt + qlog * 8;
    GLDS(gA0, ldsA0);
    GLDS(gA0 + (size_t)64 * K, ldsA1);
    GLDS(gB0, ldsB0);
    GLDS(gB0 + (size_t)64 * K, ldsB1);
    __syncthreads();

    short8 af[4], bf[4];
#pragma unroll
    for (int i = 0; i < 4; ++i) {
      int r  = wrow + 16 * i + frow;
      int rn = wcol + 16 * i + frow;
      af[i] = *(const short8*)(sA + r  * 32 + ((fq ^ ((r  >> 2) & 3)) * 8));
      bf[i] = *(const short8*)(sB + rn * 32 + ((fq ^ ((rn >> 2) & 3)) * 8));
    }
#pragma unroll
    for (int i = 0; i < 4; ++i)
#pragma unroll
      for (int j = 0; j < 4; ++j)
        acc[i][j] = __builtin_amdgcn_mfma_f32_16x16x32_bf16(af[i], bf[j], acc[i][j], 0, 0, 0);
    __syncthreads();
  }

  const int r0 = (lane >> 4) * 4;
  const int cc = lane & 15;
  unsigned short* xgd = xg + (size_t)dir * M_ * G4;
#pragma unroll
  for (int j = 0; j < 4; ++j) {
    int gcol = Ncol0 + wcol + 16 * j + cc;
    float bs = bias[dir * G4 + gcol];
#pragma unroll
    for (int i = 0; i < 4; ++i) {
      size_t rowb = Arow0 + wrow + 16 * i + r0;
#pragma unroll
      for (int r = 0; r < 4; ++r)
        xgd[(rowb + r) * G4 + gcol] = f2bf_bits(acc[i][j][r] + bs);
    }
  }
}

// ---------------------------------------------------------------------------
// Recurrent scan — R15: 4-batch MFMA scan with C-fragment redistribution.
// R14 post-mortem: 8 blocks concentrated 2048 cell-updates/CU/step -> trans
// unit issue-saturated (active-CU VALUBusy ~81%). Fix: 4 batches/block =
// 32 blocks (2dir x 16 groups), MFMA rows 0-3 real / 4-15 zero (MFMA waste
// is free: MfmaUtil was 0.4%). After MFMA, C rows 0-3 live only on lane
// quarter 0; redistribute via 4 ds_bpermute + 3 cndmask per gate so EVERY
// lane owns exactly 1 cell (batch = lq, unit = 16w + cc) -> 512 cells on
// 512 lanes, per-SIMD cell issue ~1/8 of R14. 8 waves (2/SIMD) so the two
// waves hide each other's dependent-chain stalls between barriers.
// All MFMA mappings / prep layouts carried unchanged from R14 (verified,
// absmax 9.8e-4 passed).
__global__ __attribute__((amdgpu_flat_work_group_size(512, 512))) void k_scan(
    const unsigned int* __restrict__ wf,   // packed f16 B-frags (k_prep_whh)
    const float* __restrict__ hx0,         // [2][B_][H_] (layer base)
    const float* __restrict__ cx0,
    const unsigned short* __restrict__ xg, // [2][M_][G4] bf16 gate-major
    unsigned short* __restrict__ y)        // [B_][T_][2*H_] bf16
{
  const int dir = blockIdx.x >> 4;          // 32 blocks: 2 dirs x 16 groups
  const int b0  = (blockIdx.x & 15) * 4;    // batch group base (4 batches)
  const int tid  = threadIdx.x;
  const int lane = tid & 63;
  const int w    = tid >> 6;                // wave 0..7 = 16-unit tile
  const int lq   = lane >> 4;               // lane quarter = this lane's batch
  const int cc   = lane & 15;
  const int u    = 16 * w + cc;             // this lane's unit column

  __shared__ __align__(16) unsigned short Hs[2][16 * 128];  // f16, swizzled

  // Resident weights: B-frags for 4 gates x 4 k-slices (64 VGPR).
  half8 wB[4][4];
  {
    const uint4* wv = (const uint4*)wf;
    const int base = (dir * 8 + w) * 16;
#pragma unroll
    for (int g = 0; g < 4; ++g)
#pragma unroll
      for (int kk = 0; kk < 4; ++kk)
        wB[g][kk] = __builtin_bit_cast(half8, wv[(base + g * 4 + kk) * 64 + lane]);
  }

  // c state: 1 cell per lane (batch b0+lq, unit u).
  float c = cx0[(size_t)dir * B_ * H_ + (b0 + lq) * H_ + u];

  // H init: zero both buffers (rows 4-15 must stay zero forever), then
  // rows 0-3 of buf0 from hx. Zeros are swizzle-invariant.
  ((uint4*)Hs)[tid] = (uint4){0, 0, 0, 0};   // 512 x 16B = 8 KiB exactly
  __syncthreads();
  {
    int row = tid >> 7;          // 0..3
    int col = tid & 127;
    float hv = hx0[(size_t)dir * B_ * H_ + (b0 + row) * H_ + col];
    int byteoff = (row * 256 + col * 2) ^ ((row & 7) << 4);
    *(unsigned short*)((char*)&Hs[0][0] + byteoff) =
        (unsigned short)(pack_f16x2(hv, 0.0f) & 0xFFFF);
  }

  // Loop-invariant addresses.
  int aoff[4];                               // A-frag ds_read_b128 byte offsets
#pragma unroll
  for (int kk = 0; kk < 4; ++kk)
    aoff[kk] = (cc * 256 + kk * 64 + lq * 16) ^ ((cc & 7) << 4);

  const int hwbyte = ((lq * 256 + u * 2) ^ (lq << 4));  // h write byte offset
  const int bpidx  = cc << 2;                // ds_bpermute source = lane cc

  const unsigned short* xgd = xg + (size_t)dir * M_ * G4;
  int xofs[4];                               // [gate]
#pragma unroll
  for (int g = 0; g < 4; ++g)
    xofs[g] = (b0 + lq) * (T_ * G4) + g * H_ + u;

  const int yofs = (b0 + lq) * (T_ * 2 * H_) + dir * H_ + u;

  const int td = dir ? -1 : 1;
  int t0 = dir ? (T_ - 1) : 0;

  // xg register prefetch, distance 2 (overruns stay inside the xg buffer).
  unsigned short xpA[4], xpB[4];
  {
    const unsigned short* p0 = xgd + (intptr_t)t0 * G4;
    const unsigned short* p1 = xgd + (intptr_t)(t0 + td) * G4;
#pragma unroll
    for (int g = 0; g < 4; ++g) {
      xpA[g] = p0[xofs[g]];
      xpB[g] = p1[xofs[g]];
    }
  }

  __syncthreads();   // init h visible (full drain fine, once)

  auto step = [&](int par, int tcur, unsigned short (&xp)[4]) {
    // A fragments (h_{t-1}) + MFMA: 4 gates x 4 k-slices.
    half8 a[4];
#pragma unroll
    for (int kk = 0; kk < 4; ++kk)
      a[kk] = __builtin_bit_cast(half8,
          *(const uint4*)((const char*)&Hs[par][0] + aoff[kk]));
    floatx4 ac[4];
#pragma unroll
    for (int g = 0; g < 4; ++g) ac[g] = (floatx4)0.0f;
#pragma unroll
    for (int kk = 0; kk < 4; ++kk)
#pragma unroll
      for (int g = 0; g < 4; ++g)
        ac[g] = __builtin_amdgcn_mfma_f32_16x16x32_f16(a[kk], wB[g][kk], ac[g], 0, 0, 0);

    // Capture xg(t), then prefetch xg(t+2) into the same regs.
    float xv[4];
#pragma unroll
    for (int g = 0; g < 4; ++g) xv[g] = bf_bits2f(xp[g]);
    {
      const unsigned short* pn = xgd + (intptr_t)(tcur + 2 * td) * G4;
#pragma unroll
      for (int g = 0; g < 4; ++g) xp[g] = pn[xofs[g]];
    }

    // Redistribute C rows 0-3 (held by quarter-0 lanes) to all quarters:
    // lane (q<<4)|cc takes row q of column cc. 4 bpermute + 3 select / gate.
    float gv[4];
#pragma unroll
    for (int g = 0; g < 4; ++g) {
      int v0 = __builtin_amdgcn_ds_bpermute(bpidx, __float_as_int(ac[g][0]));
      int v1 = __builtin_amdgcn_ds_bpermute(bpidx, __float_as_int(ac[g][1]));
      int v2 = __builtin_amdgcn_ds_bpermute(bpidx, __float_as_int(ac[g][2]));
      int v3 = __builtin_amdgcn_ds_bpermute(bpidx, __float_as_int(ac[g][3]));
      int lo = (lq & 1) ? v1 : v0;
      int hi = (lq & 1) ? v3 : v2;
      int vv = (lq & 2) ? hi : lo;
      gv[g] = __int_as_float(vv) + xv[g];
    }

    // Cell update: exactly one (batch, unit) cell per lane.
    float iv = sigm(gv[0]), fv = sigm(gv[1]), gg = tanh_fast(gv[2]), ov = sigm(gv[3]);
    c = fmaf(fv, c, iv * gg);
    float h = ov * tanh_fast(c);
    *(unsigned short*)((char*)&Hs[par ^ 1][0] + hwbyte) =
        (unsigned short)(pack_f16x2(h, 0.0f) & 0xFFFF);
    y[(size_t)tcur * (2 * H_) + yofs] = f2bf_bits(h);
    barrier_lds_only();
  };

  for (int it = 0; it < T_; it += 2) {
    step(0, t0, xpA);
    step(1, t0 + td, xpB);
    t0 += 2 * td;
  }
}

// ---------------------------------------------------------------------------
// Head: out[b] = y2[b, T-1, :] . lin_w + lin_b
__global__ void k_head(const unsigned short* __restrict__ y2, const float* __restrict__ lw,
                       const float* __restrict__ lb, float* __restrict__ out) {
  int b = blockIdx.x, l = threadIdx.x;
  const unsigned short* row = y2 + ((size_t)b * T_ + (T_ - 1)) * (2 * H_);
  float s = 0;
#pragma unroll
  for (int k = 0; k < 4; ++k) s += bf_bits2f(row[l + 64 * k]) * lw[l + 64 * k];
#pragma unroll
  for (int off = 32; off > 0; off >>= 1) s += __shfl_down(s, off);
  if (l == 0) out[b] = s + lb[0];
}

// ---------------------------------------------------------------------------
static inline void run_layers(const unsigned int* const* wfs,
                              const unsigned short* x0,
                              unsigned short* y0, unsigned short* y1, unsigned short* y2,
                              const unsigned short* wb0, const unsigned short* wb1,
                              const unsigned short* wb2,
                              const float* bias0, const float* bias1, const float* bias2,
                              const float* hx, const float* cx,
                              unsigned short* xg, hipStream_t stream) {
  dim3 gg(M_ / 128, G4 / 128, 2);
  k_gemm<<<gg, 256, 0, stream>>>(x0, wb0, bias0, xg, EMB_);
  k_scan<<<32, 512, 0, stream>>>(wfs[0], hx, cx, xg, y0);
  k_gemm<<<gg, 256, 0, stream>>>(y0, wb1, bias1, xg, 2 * H_);
  k_scan<<<32, 512, 0, stream>>>(wfs[1], hx + 2 * B_ * H_, cx + 2 * B_ * H_, xg, y1);
  k_gemm<<<gg, 256, 0, stream>>>(y1, wb2, bias2, xg, 2 * H_);
  k_scan<<<32, 512, 0, stream>>>(wfs[2], hx + 4 * B_ * H_, cx + 4 * B_ * H_, xg, y2);
}

extern "C" void kernel_launch(void* const* d_in, const int* in_sizes, int n_in,
                              void* d_out, int out_size, void* d_ws, size_t ws_size,
                              hipStream_t stream) {
  const int*   X   = (const int*)d_in[0];
  const float* emb = (const float*)d_in[1];
  const float* hx  = (const float*)d_in[2];
  const float* cx  = (const float*)d_in[3];
  const float* lw  = (const float*)d_in[4];
  const float* lb  = (const float*)d_in[5];
  const float* w_ih[3] = {(const float*)d_in[6],  (const float*)d_in[10], (const float*)d_in[14]};
  const float* w_hh[3] = {(const float*)d_in[7],  (const float*)d_in[11], (const float*)d_in[15]};
  const float* b_ih[3] = {(const float*)d_in[8],  (const float*)d_in[12], (const float*)d_in[16]};
  const float* b_hh[3] = {(const float*)d_in[9],  (const float*)d_in[13], (const float*)d_in[17]};
  float* out = (float*)d_out;

  char* ws = (char*)d_ws;
  size_t off = 0;
  auto carve = [&](size_t bytes) {
    char* p = ws + off;
    off = (off + bytes + 255) & ~(size_t)255;
    return p;
  };
  unsigned short* x0  = (unsigned short*)carve((size_t)M_ * EMB_ * 2);
  unsigned short* y0  = (unsigned short*)carve((size_t)M_ * 2 * H_ * 2);
  unsigned short* y1  = (unsigned short*)carve((size_t)M_ * 2 * H_ * 2);
  unsigned short* y2  = (unsigned short*)carve((size_t)M_ * 2 * H_ * 2);
  unsigned short* wb0 = (unsigned short*)carve((size_t)2 * G4 * EMB_ * 2);
  unsigned short* wb1 = (unsigned short*)carve((size_t)2 * G4 * 2 * H_ * 2);
  unsigned short* wb2 = (unsigned short*)carve((size_t)2 * G4 * 2 * H_ * 2);
  float* bias0 = (float*)carve(2 * G4 * 4);
  float* bias1 = (float*)carve(2 * G4 * 4);
  float* bias2 = (float*)carve(2 * G4 * 4);
  unsigned int* wf0 = (unsigned int*)carve((size_t)65536 * 4);
  unsigned int* wf1 = (unsigned int*)carve((size_t)65536 * 4);
  unsigned int* wf2 = (unsigned int*)carve((size_t)65536 * 4);
  unsigned short* xg = (unsigned short*)carve((size_t)2 * M_ * G4 * 2);  // bf16

  k_prep<<<256, 256, 0, stream>>>(w_ih[0], b_ih[0], b_hh[0], wb0, bias0, 2 * G4 * EMB_);
  k_prep<<<256, 256, 0, stream>>>(w_ih[1], b_ih[1], b_hh[1], wb1, bias1, 2 * G4 * 2 * H_);
  k_prep<<<256, 256, 0, stream>>>(w_ih[2], b_ih[2], b_hh[2], wb2, bias2, 2 * G4 * 2 * H_);
  k_prep_whh<<<256, 256, 0, stream>>>(w_hh[0], wf0);
  k_prep_whh<<<256, 256, 0, stream>>>(w_hh[1], wf1);
  k_prep_whh<<<256, 256, 0, stream>>>(w_hh[2], wf2);
  k_gather<<<(M_ * 32) / 256, 256, 0, stream>>>(X, emb, x0);

  const unsigned int* wfs[3] = {wf0, wf1, wf2};
  run_layers(wfs, x0, y0, y1, y2, wb0, wb1, wb2, bias0, bias1, bias2,
             hx, cx, xg, stream);

  k_head<<<64, 64, 0, stream>>>(y2, lw, lb, out);
}